// Round 1
// 1950.210 us; speedup vs baseline: 1.0186x; 1.0186x over previous
//
#include <hip/hip_runtime.h>
#include <hip/hip_bf16.h>
#include <math.h>

#define N_NODES 20000
#define N_EDGES 40000
#define N_SEG   (N_NODES + N_EDGES)
#define CAP     64
#define DIM     512

typedef __attribute__((ext_vector_type(8))) short short8;
typedef __attribute__((ext_vector_type(4))) float floatx4;

__device__ __forceinline__ unsigned short f2b(float f) {
    union { float f; unsigned int i; } v; v.f = f;
    unsigned int i = v.i;
    unsigned int r = (i + 0x7fffu + ((i >> 16) & 1u)) >> 16;
    return (unsigned short)r;
}

// ---------------- K1: logits (2 rows/wave) + exp + segment sums + index/weight lists
//                  tail blocks (>= nbl): transpose proj_w -> Wt bf16 ----------------
__global__ __launch_bounds__(256) void k_front(
    const float* __restrict__ feat,
    const float* __restrict__ attn_w,
    const float* __restrict__ attn_b,
    const int* __restrict__ m2m,
    const float* __restrict__ W,          // proj_w fp32 [512][512]
    float* __restrict__ seg_sum,
    int* __restrict__ seg_cnt,
    int* __restrict__ perm,
    float* __restrict__ eperm,
    unsigned short* __restrict__ Wt,      // [n][k] bf16
    int n_micro, int nbl)
{
    __shared__ float tile[64][68];
    int t = threadIdx.x;

    if (blockIdx.x >= (unsigned)nbl) {
        // -------- transpose path (64 blocks) --------
        int b = blockIdx.x - nbl;
        int bx = b & 7, by = b >> 3;
        int r0 = by * 64, c0 = bx * 64;   // r0: k-range, c0: n-range
#pragma unroll
        for (int i = 0; i < 4; ++i) {
            int idx = i * 256 + t;
            int r = idx >> 4, ch = (idx & 15) * 4;
            *(float4*)&tile[r][ch] = *(const float4*)&W[(size_t)(r0 + r) * 512 + c0 + ch];
        }
        __syncthreads();
#pragma unroll
        for (int i = 0; i < 2; ++i) {
            int idx = i * 256 + t;
            int n = idx >> 3, kc = (idx & 7) * 8;
            union { unsigned short us[8]; uint4 v; } o;
#pragma unroll
            for (int j = 0; j < 8; ++j) o.us[j] = f2b(tile[kc + j][n]);
            *(uint4*)&Wt[(size_t)(c0 + n) * 512 + r0 + kc] = o.v;
        }
        return;
    }

    // -------- logits path: each wave handles rows row0, row0+1 --------
    int lane = t & 63;
    int row0 = (blockIdx.x * 4 + (t >> 6)) * 2;
    if (row0 >= n_micro) return;
    bool has1 = (row0 + 1) < n_micro;

    float4 w0 = *(const float4*)&attn_w[lane * 8];
    float4 w1 = *(const float4*)&attn_w[lane * 8 + 4];

    const float* fr0 = &feat[(size_t)row0 * DIM + lane * 8];
    float4 a0 = *(const float4*)fr0;
    float4 a1 = *(const float4*)(fr0 + 4);
    float4 b0 = make_float4(0, 0, 0, 0), b1 = make_float4(0, 0, 0, 0);
    if (has1) {
        b0 = *(const float4*)(fr0 + DIM);
        b1 = *(const float4*)(fr0 + DIM + 4);
    }

    float p0 = 0.f, p1 = 0.f;
    p0 = fmaf(a0.x, w0.x, p0); p0 = fmaf(a0.y, w0.y, p0);
    p0 = fmaf(a0.z, w0.z, p0); p0 = fmaf(a0.w, w0.w, p0);
    p0 = fmaf(a1.x, w1.x, p0); p0 = fmaf(a1.y, w1.y, p0);
    p0 = fmaf(a1.z, w1.z, p0); p0 = fmaf(a1.w, w1.w, p0);
    p1 = fmaf(b0.x, w0.x, p1); p1 = fmaf(b0.y, w0.y, p1);
    p1 = fmaf(b0.z, w0.z, p1); p1 = fmaf(b0.w, w0.w, p1);
    p1 = fmaf(b1.x, w1.x, p1); p1 = fmaf(b1.y, w1.y, p1);
    p1 = fmaf(b1.z, w1.z, p1); p1 = fmaf(b1.w, w1.w, p1);
#pragma unroll
    for (int d = 32; d > 0; d >>= 1) {
        p0 += __shfl_xor(p0, d);
        p1 += __shfl_xor(p1, d);
    }

    // lanes 0 and 32 finish the two rows in parallel
    if ((lane & 31) == 0) {
        int row = row0 + (lane >> 5);
        if (row < n_micro) {
            float pv = (lane == 0) ? p0 : p1;
            float e = expf(pv + attn_b[0]);
            int m = m2m[row];
            int seg = -1;
            if (m >= 0) seg = m;
            else if (m != -100) seg = N_NODES + (-m - 1);
            if (seg >= 0) {
                atomicAdd(&seg_sum[seg], e);
                int pos = atomicAdd(&seg_cnt[seg], 1);
                if (pos < CAP) {
                    perm[seg * CAP + pos]  = row;
                    eperm[seg * CAP + pos] = e;
                }
            }
        }
    }
}

// ---------------- K2: weighted aggregation, one wave per segment ----------------
__global__ __launch_bounds__(256) void k_agg(
    const float* __restrict__ feat,
    const float* __restrict__ seg_sum,
    const int* __restrict__ seg_cnt,
    const int* __restrict__ perm,
    const float* __restrict__ eperm,
    unsigned short* __restrict__ agg)   // bf16 out [N_SEG][512]
{
    int lane = threadIdx.x & 63;
    int seg  = blockIdx.x * 4 + (threadIdx.x >> 6);
    if (seg >= N_SEG) return;

    int cnt = seg_cnt[seg];
    if (cnt > CAP) cnt = CAP;
    float sinv = 1.0f / (seg_sum[seg] + 1e-8f);

    int   myidx = (lane < cnt) ? perm[seg * CAP + lane]  : 0;
    float mye   = (lane < cnt) ? eperm[seg * CAP + lane] : 0.f;

    float acc[8] = {0.f, 0.f, 0.f, 0.f, 0.f, 0.f, 0.f, 0.f};
    float4 c0 = make_float4(0, 0, 0, 0), c1 = make_float4(0, 0, 0, 0);
    if (cnt > 0) {
        int i0 = __shfl(myidx, 0);
        const float* fr = &feat[(size_t)i0 * DIM + lane * 8];
        c0 = *(const float4*)fr; c1 = *(const float4*)(fr + 4);
    }
    for (int j = 0; j < cnt; ++j) {
        float4 n0 = c0, n1 = c1;
        if (j + 1 < cnt) {
            int i1 = __shfl(myidx, j + 1);
            const float* fr = &feat[(size_t)i1 * DIM + lane * 8];
            n0 = *(const float4*)fr; n1 = *(const float4*)(fr + 4);
        }
        float w = __shfl(mye, j) * sinv;
        acc[0] = fmaf(w, c0.x, acc[0]); acc[1] = fmaf(w, c0.y, acc[1]);
        acc[2] = fmaf(w, c0.z, acc[2]); acc[3] = fmaf(w, c0.w, acc[3]);
        acc[4] = fmaf(w, c1.x, acc[4]); acc[5] = fmaf(w, c1.y, acc[5]);
        acc[6] = fmaf(w, c1.z, acc[6]); acc[7] = fmaf(w, c1.w, acc[7]);
        c0 = n0; c1 = n1;
    }
    union { unsigned short us[8]; uint4 v; } o;
#pragma unroll
    for (int k = 0; k < 8; ++k) o.us[k] = f2b(acc[k]);
    *(uint4*)&agg[(size_t)seg * DIM + lane * 8] = o.v;
}

// ---------------- K3: GEMM (agg @ W) + bias + LayerNorm + exact GELU, M=64 ----------------
__global__ __launch_bounds__(256, 2) void k_proj(
    const unsigned short* __restrict__ A,    // agg [N_SEG][512] bf16
    const unsigned short* __restrict__ Wt,   // [512 n][512 k] bf16
    const float* __restrict__ pb,            // proj_b [512]
    const float* __restrict__ lg,            // ln_g [512]
    const float* __restrict__ lb,            // ln_b [512]
    float* __restrict__ out)                 // [N_SEG][512] fp32
{
    __shared__ union {
        struct { unsigned short a[64 * 40]; unsigned short b[512 * 40]; } st;   // 51200 B
        struct { float h[16 * 516]; float ps[16][17]; float ps2[16][17];
                 float mu[16]; float rs[16]; } ep;                              // 35328 B
    } u;

    int t = threadIdx.x;
    int w = t >> 6, lane = t & 63;
    int quad = lane >> 4, l15 = lane & 15;
    int bm0 = blockIdx.x * 64;

    floatx4 acc[4][8];
#pragma unroll
    for (int mt = 0; mt < 4; ++mt)
#pragma unroll
        for (int nt = 0; nt < 8; ++nt)
            acc[mt][nt] = (floatx4){0.f, 0.f, 0.f, 0.f};

    for (int kk = 0; kk < 512; kk += 32) {
        {
            int r = t >> 2, k8 = (t & 3) * 8;   // 64 rows x 32 k, over-read past N_SEG stays in ws
            *(uint4*)&u.st.a[r * 40 + k8] = *(const uint4*)&A[(size_t)(bm0 + r) * 512 + kk + k8];
        }
#pragma unroll
        for (int i = 0; i < 8; ++i) {
            int c = i * 256 + t;
            int n = c >> 2, k8 = (c & 3) * 8;
            *(uint4*)&u.st.b[n * 40 + k8] = *(const uint4*)&Wt[(size_t)n * 512 + kk + k8];
        }
        __syncthreads();

        int kb = quad * 8;
        short8 af[4], bf[8];
#pragma unroll
        for (int mt = 0; mt < 4; ++mt)
            af[mt] = *(const short8*)&u.st.a[(mt * 16 + l15) * 40 + kb];
#pragma unroll
        for (int nt = 0; nt < 8; ++nt)
            bf[nt] = *(const short8*)&u.st.b[(w * 128 + nt * 16 + l15) * 40 + kb];
#pragma unroll
        for (int mt = 0; mt < 4; ++mt)
#pragma unroll
            for (int nt = 0; nt < 8; ++nt)
                acc[mt][nt] = __builtin_amdgcn_mfma_f32_16x16x32_bf16(af[mt], bf[nt], acc[mt][nt], 0, 0, 0);
        __syncthreads();
    }

    // Epilogue: four phases of 16 rows each (N_SEG % 16 == 0, so phases are all-valid or skipped)
#pragma unroll 1
    for (int mt = 0; mt < 4; ++mt) {
        if (bm0 + mt * 16 >= N_SEG) break;   // block-uniform
        __syncthreads();   // previous phase (or K-loop) LDS reads complete
        // write h (+ proj_b); C/D layout: n = lane&15, m = quad*4 + r
#pragma unroll
        for (int nt = 0; nt < 8; ++nt) {
            int col = w * 128 + nt * 16 + l15;
            float pbv = pb[col];
#pragma unroll
            for (int r = 0; r < 4; ++r) {
                int row = quad * 4 + r;
                u.ep.h[row * 516 + col] = acc[mt][nt][r] + pbv;
            }
        }
        __syncthreads();

        // LN stats: 16 partials per row (each covers 32 cols)
        {
            int row = t & 15, part = t >> 4;
            float s = 0.f, s2 = 0.f;
#pragma unroll
            for (int c4 = 0; c4 < 8; ++c4) {
                float4 v = *(const float4*)&u.ep.h[row * 516 + part * 32 + c4 * 4];
                s  += v.x + v.y + v.z + v.w;
                s2 += v.x * v.x + v.y * v.y + v.z * v.z + v.w * v.w;
            }
            u.ep.ps[part][row]  = s;
            u.ep.ps2[part][row] = s2;
        }
        __syncthreads();
        if (t < 16) {
            float S = 0.f, S2 = 0.f;
#pragma unroll
            for (int p = 0; p < 16; ++p) { S += u.ep.ps[p][t]; S2 += u.ep.ps2[p][t]; }
            float mu  = S * (1.0f / 512.0f);
            float var = S2 * (1.0f / 512.0f) - mu * mu;
            u.ep.mu[t] = mu;
            u.ep.rs[t] = rsqrtf(fmaxf(var, 0.f) + 1e-5f);
        }
        __syncthreads();

        // LN + exact GELU + fp32 store, coalesced
#pragma unroll
        for (int i = 0; i < 8; ++i) {
            int c = i * 256 + t;               // 0..2047 float4s
            int r = c >> 7, c4 = (c & 127) * 4;
            float4 v = *(const float4*)&u.ep.h[r * 516 + c4];
            float mu = u.ep.mu[r], rs = u.ep.rs[r];
            float vv[4] = {v.x, v.y, v.z, v.w};
            float4 o;
            float* op = &o.x;
#pragma unroll
            for (int j = 0; j < 4; ++j) {
                float x = (vv[j] - mu) * rs * lg[c4 + j] + lb[c4 + j];
                op[j] = 0.5f * x * (1.0f + erff(x * 0.70710678118f));
            }
            *(float4*)&out[(size_t)(bm0 + mt * 16 + r) * 512 + c4] = o;
        }
    }
}

extern "C" void kernel_launch(void* const* d_in, const int* in_sizes, int n_in,
                              void* d_out, int out_size, void* d_ws, size_t ws_size,
                              hipStream_t stream)
{
    const float* feat   = (const float*)d_in[0];
    const float* attn_w = (const float*)d_in[1];
    const float* attn_b = (const float*)d_in[2];
    const float* proj_w = (const float*)d_in[3];
    const float* proj_b = (const float*)d_in[4];
    const float* ln_g   = (const float*)d_in[5];
    const float* ln_b   = (const float*)d_in[6];
    const int*   m2m    = (const int*)d_in[7];
    float* out          = (float*)d_out;

    int n_micro = in_sizes[0] / DIM;

    char* ws = (char*)d_ws;
    float* seg_sum = (float*)ws;
    int*   seg_cnt = (int*)(seg_sum + N_SEG);
    int*   perm    = seg_cnt + N_SEG;
    float* eperm   = (float*)(perm + (size_t)N_SEG * CAP);
    unsigned short* Wt  = (unsigned short*)(eperm + (size_t)N_SEG * CAP);
    unsigned short* agg = Wt + 512 * 512;

    int nbl = (n_micro + 7) / 8;   // 8 rows per block (4 waves x 2 rows)

    hipMemsetAsync(seg_sum, 0, (size_t)N_SEG * 2 * sizeof(float), stream);
    k_front<<<nbl + 64, 256, 0, stream>>>(feat, attn_w, attn_b, m2m, proj_w,
                                          seg_sum, seg_cnt, perm, eperm, Wt,
                                          n_micro, nbl);
    k_agg<<<(N_SEG + 3) / 4, 256, 0, stream>>>(feat, seg_sum, seg_cnt, perm, eperm, agg);
    k_proj<<<(N_SEG + 63) / 64, 256, 0, stream>>>(agg, Wt, proj_b, ln_g, ln_b, out);
    (void)n_in; (void)out_size; (void)ws_size;
}

// Round 2
// 1781.217 us; speedup vs baseline: 1.1152x; 1.0949x over previous
//
#include <hip/hip_runtime.h>
#include <hip/hip_bf16.h>
#include <math.h>

#define N_NODES 20000
#define N_EDGES 40000
#define N_SEG   (N_NODES + N_EDGES)
#define CAP     64
#define DIM     512

typedef __attribute__((ext_vector_type(8))) short short8;
typedef __attribute__((ext_vector_type(4))) float floatx4;

__device__ __forceinline__ unsigned short f2b(float f) {
    union { float f; unsigned int i; } v; v.f = f;
    unsigned int i = v.i;
    unsigned int r = (i + 0x7fffu + ((i >> 16) & 1u)) >> 16;
    return (unsigned short)r;
}

// ---------------- K1: bucketing (no feat read) + transpose tail blocks ----------------
__global__ __launch_bounds__(256) void k_front(
    const int* __restrict__ m2m,
    const float* __restrict__ W,          // proj_w fp32 [512][512]
    int* __restrict__ seg_cnt,
    int* __restrict__ perm,
    unsigned short* __restrict__ Wt,      // [n][k] bf16
    int n_micro, int nbl)
{
    __shared__ float tile[64][68];
    int t = threadIdx.x;

    if (blockIdx.x >= (unsigned)nbl) {
        // -------- transpose path (64 blocks) --------
        int b = blockIdx.x - nbl;
        int bx = b & 7, by = b >> 3;
        int r0 = by * 64, c0 = bx * 64;   // r0: k-range, c0: n-range
#pragma unroll
        for (int i = 0; i < 4; ++i) {
            int idx = i * 256 + t;
            int r = idx >> 4, ch = (idx & 15) * 4;
            *(float4*)&tile[r][ch] = *(const float4*)&W[(size_t)(r0 + r) * 512 + c0 + ch];
        }
        __syncthreads();
#pragma unroll
        for (int i = 0; i < 2; ++i) {
            int idx = i * 256 + t;
            int n = idx >> 3, kc = (idx & 7) * 8;
            union { unsigned short us[8]; uint4 v; } o;
#pragma unroll
            for (int j = 0; j < 8; ++j) o.us[j] = f2b(tile[kc + j][n]);
            *(uint4*)&Wt[(size_t)(c0 + n) * 512 + r0 + kc] = o.v;
        }
        return;
    }

    // -------- bucketing path: one thread per micro row --------
    int row = blockIdx.x * 256 + t;
    if (row >= n_micro) return;
    int m = m2m[row];
    int seg = -1;
    if (m >= 0) seg = m;
    else if (m != -100) seg = N_NODES + (-m - 1);
    if (seg >= 0) {
        int pos = atomicAdd(&seg_cnt[seg], 1);
        if (pos < CAP) perm[seg * CAP + pos] = row;
    }
}

// ---------------- K2: gather + inline logits + online weighted aggregation ----------------
// One wave per segment. agg = (sum_j e_j * x_j) / (sum_j e_j + eps) -- normalization is
// linear, so no pre-pass over feat is needed; e_j computed from the gathered row itself.
__global__ __launch_bounds__(256) void k_agg(
    const float* __restrict__ feat,
    const float* __restrict__ attn_w,
    const float* __restrict__ attn_b,
    const int* __restrict__ seg_cnt,
    const int* __restrict__ perm,
    unsigned short* __restrict__ agg)   // bf16 out [N_SEG][512]
{
    int lane = threadIdx.x & 63;
    int seg  = blockIdx.x * 4 + (threadIdx.x >> 6);
    if (seg >= N_SEG) return;

    int cnt = seg_cnt[seg];
    if (cnt > CAP) cnt = CAP;

    float4 w0 = *(const float4*)&attn_w[lane * 8];
    float4 w1 = *(const float4*)&attn_w[lane * 8 + 4];
    float ab = attn_b[0];

    int myidx = (lane < cnt) ? perm[seg * CAP + lane] : 0;

    float acc[8] = {0.f, 0.f, 0.f, 0.f, 0.f, 0.f, 0.f, 0.f};
    float ssum = 0.f;
    float4 c0 = make_float4(0, 0, 0, 0), c1 = make_float4(0, 0, 0, 0);
    if (cnt > 0) {
        int i0 = __shfl(myidx, 0);
        const float* fr = &feat[(size_t)i0 * DIM + lane * 8];
        c0 = *(const float4*)fr; c1 = *(const float4*)(fr + 4);
    }
    for (int j = 0; j < cnt; ++j) {
        // prefetch next row first (independent of the reduce chain below)
        float4 n0 = c0, n1 = c1;
        if (j + 1 < cnt) {
            int i1 = __shfl(myidx, j + 1);
            const float* fr = &feat[(size_t)i1 * DIM + lane * 8];
            n0 = *(const float4*)fr; n1 = *(const float4*)(fr + 4);
        }
        // logit of row j from the data we already hold (same op order as before)
        float p = 0.f;
        p = fmaf(c0.x, w0.x, p); p = fmaf(c0.y, w0.y, p);
        p = fmaf(c0.z, w0.z, p); p = fmaf(c0.w, w0.w, p);
        p = fmaf(c1.x, w1.x, p); p = fmaf(c1.y, w1.y, p);
        p = fmaf(c1.z, w1.z, p); p = fmaf(c1.w, w1.w, p);
#pragma unroll
        for (int d = 32; d > 0; d >>= 1) p += __shfl_xor(p, d);
        float e = expf(p + ab);
        ssum += e;
        acc[0] = fmaf(e, c0.x, acc[0]); acc[1] = fmaf(e, c0.y, acc[1]);
        acc[2] = fmaf(e, c0.z, acc[2]); acc[3] = fmaf(e, c0.w, acc[3]);
        acc[4] = fmaf(e, c1.x, acc[4]); acc[5] = fmaf(e, c1.y, acc[5]);
        acc[6] = fmaf(e, c1.z, acc[6]); acc[7] = fmaf(e, c1.w, acc[7]);
        c0 = n0; c1 = n1;
    }
    float sinv = 1.0f / (ssum + 1e-8f);
    union { unsigned short us[8]; uint4 v; } o;
#pragma unroll
    for (int k = 0; k < 8; ++k) o.us[k] = f2b(acc[k] * sinv);
    *(uint4*)&agg[(size_t)seg * DIM + lane * 8] = o.v;
}

// ---------------- K3: GEMM (agg @ W) + bias + LayerNorm + exact GELU, M=64 ----------------
__global__ __launch_bounds__(256, 2) void k_proj(
    const unsigned short* __restrict__ A,    // agg [N_SEG][512] bf16
    const unsigned short* __restrict__ Wt,   // [512 n][512 k] bf16
    const float* __restrict__ pb,            // proj_b [512]
    const float* __restrict__ lg,            // ln_g [512]
    const float* __restrict__ lb,            // ln_b [512]
    float* __restrict__ out)                 // [N_SEG][512] fp32
{
    __shared__ union {
        struct { unsigned short a[64 * 40]; unsigned short b[512 * 40]; } st;   // 51200 B
        struct { float h[16 * 516]; float ps[16][17]; float ps2[16][17];
                 float mu[16]; float rs[16]; } ep;                              // 35328 B
    } u;

    int t = threadIdx.x;
    int w = t >> 6, lane = t & 63;
    int quad = lane >> 4, l15 = lane & 15;
    int bm0 = blockIdx.x * 64;

    floatx4 acc[4][8];
#pragma unroll
    for (int mt = 0; mt < 4; ++mt)
#pragma unroll
        for (int nt = 0; nt < 8; ++nt)
            acc[mt][nt] = (floatx4){0.f, 0.f, 0.f, 0.f};

    for (int kk = 0; kk < 512; kk += 32) {
        {
            int r = t >> 2, k8 = (t & 3) * 8;
            *(uint4*)&u.st.a[r * 40 + k8] = *(const uint4*)&A[(size_t)(bm0 + r) * 512 + kk + k8];
        }
#pragma unroll
        for (int i = 0; i < 8; ++i) {
            int c = i * 256 + t;
            int n = c >> 2, k8 = (c & 3) * 8;
            *(uint4*)&u.st.b[n * 40 + k8] = *(const uint4*)&Wt[(size_t)n * 512 + kk + k8];
        }
        __syncthreads();

        int kb = quad * 8;
        short8 af[4], bf[8];
#pragma unroll
        for (int mt = 0; mt < 4; ++mt)
            af[mt] = *(const short8*)&u.st.a[(mt * 16 + l15) * 40 + kb];
#pragma unroll
        for (int nt = 0; nt < 8; ++nt)
            bf[nt] = *(const short8*)&u.st.b[(w * 128 + nt * 16 + l15) * 40 + kb];
#pragma unroll
        for (int mt = 0; mt < 4; ++mt)
#pragma unroll
            for (int nt = 0; nt < 8; ++nt)
                acc[mt][nt] = __builtin_amdgcn_mfma_f32_16x16x32_bf16(af[mt], bf[nt], acc[mt][nt], 0, 0, 0);
        __syncthreads();
    }

    // Epilogue: four phases of 16 rows each
#pragma unroll 1
    for (int mt = 0; mt < 4; ++mt) {
        if (bm0 + mt * 16 >= N_SEG) break;   // block-uniform
        __syncthreads();
#pragma unroll
        for (int nt = 0; nt < 8; ++nt) {
            int col = w * 128 + nt * 16 + l15;
            float pbv = pb[col];
#pragma unroll
            for (int r = 0; r < 4; ++r) {
                int row = quad * 4 + r;
                u.ep.h[row * 516 + col] = acc[mt][nt][r] + pbv;
            }
        }
        __syncthreads();

        {
            int row = t & 15, part = t >> 4;
            float s = 0.f, s2 = 0.f;
#pragma unroll
            for (int c4 = 0; c4 < 8; ++c4) {
                float4 v = *(const float4*)&u.ep.h[row * 516 + part * 32 + c4 * 4];
                s  += v.x + v.y + v.z + v.w;
                s2 += v.x * v.x + v.y * v.y + v.z * v.z + v.w * v.w;
            }
            u.ep.ps[part][row]  = s;
            u.ep.ps2[part][row] = s2;
        }
        __syncthreads();
        if (t < 16) {
            float S = 0.f, S2 = 0.f;
#pragma unroll
            for (int p = 0; p < 16; ++p) { S += u.ep.ps[p][t]; S2 += u.ep.ps2[p][t]; }
            float mu  = S * (1.0f / 512.0f);
            float var = S2 * (1.0f / 512.0f) - mu * mu;
            u.ep.mu[t] = mu;
            u.ep.rs[t] = rsqrtf(fmaxf(var, 0.f) + 1e-5f);
        }
        __syncthreads();

#pragma unroll
        for (int i = 0; i < 8; ++i) {
            int c = i * 256 + t;
            int r = c >> 7, c4 = (c & 127) * 4;
            float4 v = *(const float4*)&u.ep.h[r * 516 + c4];
            float mu = u.ep.mu[r], rs = u.ep.rs[r];
            float vv[4] = {v.x, v.y, v.z, v.w};
            float4 o;
            float* op = &o.x;
#pragma unroll
            for (int j = 0; j < 4; ++j) {
                float x = (vv[j] - mu) * rs * lg[c4 + j] + lb[c4 + j];
                op[j] = 0.5f * x * (1.0f + erff(x * 0.70710678118f));
            }
            *(float4*)&out[(size_t)(bm0 + mt * 16 + r) * 512 + c4] = o;
        }
    }
}

extern "C" void kernel_launch(void* const* d_in, const int* in_sizes, int n_in,
                              void* d_out, int out_size, void* d_ws, size_t ws_size,
                              hipStream_t stream)
{
    const float* feat   = (const float*)d_in[0];
    const float* attn_w = (const float*)d_in[1];
    const float* attn_b = (const float*)d_in[2];
    const float* proj_w = (const float*)d_in[3];
    const float* proj_b = (const float*)d_in[4];
    const float* ln_g   = (const float*)d_in[5];
    const float* ln_b   = (const float*)d_in[6];
    const int*   m2m    = (const int*)d_in[7];
    float* out          = (float*)d_out;

    int n_micro = in_sizes[0] / DIM;

    char* ws = (char*)d_ws;
    int*   seg_cnt = (int*)ws;
    int*   perm    = seg_cnt + N_SEG;
    unsigned short* Wt  = (unsigned short*)(perm + (size_t)N_SEG * CAP);
    unsigned short* agg = Wt + 512 * 512;

    int nbl = (n_micro + 255) / 256;

    hipMemsetAsync(seg_cnt, 0, (size_t)N_SEG * sizeof(int), stream);
    k_front<<<nbl + 64, 256, 0, stream>>>(m2m, proj_w, seg_cnt, perm, Wt, n_micro, nbl);
    k_agg<<<(N_SEG + 3) / 4, 256, 0, stream>>>(feat, attn_w, attn_b, seg_cnt, perm, agg);
    k_proj<<<(N_SEG + 63) / 64, 256, 0, stream>>>(agg, Wt, proj_b, ln_g, ln_b, out);
    (void)n_in; (void)out_size; (void)ws_size;
}